// Round 1
// baseline (369.454 us; speedup 1.0000x reference)
//
#include <hip/hip_runtime.h>
#include <stdint.h>

#define BATCH   32768
#define NSUP    256
#define NSUB    1024
#define LATENT  512
#define NOUT    200
#define M_EXT   (BATCH + NSUP)          // 33024 = 258*128
#define SUP_OFF ((size_t)BATCH * NOUT)  // sup_out offset in d_out

typedef unsigned short u16;
typedef __attribute__((ext_vector_type(8))) __bf16 bf16x8;
typedef __attribute__((ext_vector_type(4))) float  floatx4;

typedef const __attribute__((address_space(1))) void* gptr_t;
typedef __attribute__((address_space(3))) void* sptr_t;

__device__ __forceinline__ void gload16(const void* g, void* l) {
  __builtin_amdgcn_global_load_lds((gptr_t)g, (sptr_t)l, 16, 0, 0);
}

__device__ __forceinline__ floatx4 mfma_bf16(bf16x8 a, bf16x8 b, floatx4 c) {
  return __builtin_amdgcn_mfma_f32_16x16x32_bf16(a, b, c, 0, 0, 0);
}

__device__ __forceinline__ u16 f2bf(float f) {
  unsigned int u = __float_as_uint(f);
  u += 0x7FFFu + ((u >> 16) & 1u);   // RNE; inputs are finite, no NaN handling needed
  return (u16)(u >> 16);
}

// ---------------- conversion + row norms: fp32 (rows x 512) -> bf16, norms fp32
__global__ __launch_bounds__(256) void k_convert(const float* __restrict__ src,
    u16* __restrict__ dst, float* __restrict__ norms) {
  int row  = blockIdx.x * 4 + (threadIdx.x >> 6);
  int lane = threadIdx.x & 63;
  const float* s = src + (size_t)row * LATENT + lane * 8;
  float4 v0 = ((const float4*)s)[0];
  float4 v1 = ((const float4*)s)[1];
  float ss = v0.x*v0.x + v0.y*v0.y + v0.z*v0.z + v0.w*v0.w
           + v1.x*v1.x + v1.y*v1.y + v1.z*v1.z + v1.w*v1.w;
  uint4 o;
  o.x = (unsigned)f2bf(v0.x) | ((unsigned)f2bf(v0.y) << 16);
  o.y = (unsigned)f2bf(v0.z) | ((unsigned)f2bf(v0.w) << 16);
  o.z = (unsigned)f2bf(v1.x) | ((unsigned)f2bf(v1.y) << 16);
  o.w = (unsigned)f2bf(v1.z) | ((unsigned)f2bf(v1.w) << 16);
  *((uint4*)(dst + (size_t)row * LATENT + lane * 8)) = o;
  for (int off = 32; off; off >>= 1) ss += __shfl_down(ss, off);
  if (lane == 0) norms[row] = ss;
}

// ---------------- per-output-column constants: sc[o]=sum_j W[o,j]; cc[o]=sum_j W[o,j]*yy[j]+b[o]
__global__ __launch_bounds__(256) void k_wprep(const float* __restrict__ W1,
    const float* __restrict__ b1, const float* __restrict__ W2,
    const float* __restrict__ b2, const float* __restrict__ yy_sup,
    const float* __restrict__ yy_sub, float* __restrict__ sc, float* __restrict__ cc) {
  int o = blockIdx.x * 256 + threadIdx.x;
  if (o >= 400) return;
  float s = 0.f, c = 0.f;
  if (o < 200) {
    for (int j = 0; j < NSUP; j++) { float w = W1[o*NSUP + j]; s += w; c += w * yy_sup[j]; }
    c += b1[o];
  } else {
    int oo = o - 200;
    for (int j = 0; j < NSUB; j++) { float w = W2[oo*NSUB + j]; s += w; c += w * yy_sub[j]; }
    c += b2[oo];
  }
  sc[o] = s; cc[o] = c;
}

// ---------------- Mt[o][k] = -2 * sum_j W[o,j] * P[j,k]   (bf16, rows 400..511 zero)
__global__ __launch_bounds__(256) void k_mt(const float* __restrict__ sup,
    const float* __restrict__ sub, const float* __restrict__ W1,
    const float* __restrict__ W2, u16* __restrict__ Mt) {
  __shared__ float lw[4 * 1024];
  int k  = blockIdx.x * 256 + threadIdx.x;
  int o0 = blockIdx.y * 4;
  if (o0 >= 400) {
    for (int oo = 0; oo < 4; oo++) Mt[(size_t)(o0 + oo) * LATENT + k] = 0;
    return;
  }
  const float* P; const float* W; int n, ow;
  if (o0 < 200) { P = sup; W = W1; n = NSUP;  ow = o0; }
  else          { P = sub; W = W2; n = NSUB;  ow = o0 - 200; }
  for (int idx = threadIdx.x; idx < 4 * n; idx += 256) {
    int oo = idx / n, j = idx & (n - 1);
    lw[oo * 1024 + j] = W[(size_t)(ow + oo) * n + j];
  }
  __syncthreads();
  float a0 = 0, a1 = 0, a2 = 0, a3 = 0;
  for (int j = 0; j < n; j++) {
    float p = P[(size_t)j * LATENT + k];
    a0 += p * lw[j];
    a1 += p * lw[1024 + j];
    a2 += p * lw[2048 + j];
    a3 += p * lw[3072 + j];
  }
  Mt[(size_t)(o0 + 0) * LATENT + k] = f2bf(-2.f * a0);
  Mt[(size_t)(o0 + 1) * LATENT + k] = f2bf(-2.f * a1);
  Mt[(size_t)(o0 + 2) * LATENT + k] = f2bf(-2.f * a2);
  Mt[(size_t)(o0 + 3) * LATENT + k] = f2bf(-2.f * a3);
}

// ---------------- init min arrays to +inf bits
__global__ __launch_bounds__(256) void k_init(unsigned int* __restrict__ p, int n) {
  int i = blockIdx.x * 256 + threadIdx.x;
  if (i < n) p[i] = 0x7F800000u;
}

// ---------------- shared MFMA mainloop: 128x128 tile, K=512, BK=32
__device__ __forceinline__ void gemm_core(const u16* __restrict__ A,
    const u16* __restrict__ B, u16* lA, u16* lB,
    size_t arow0, size_t brow0, floatx4 acc[4][4]) {
  int t = threadIdx.x;
  int wave = t >> 6, lane = t & 63;
  int l16 = lane & 15, q = lane >> 4;
  int wm = (wave >> 1) * 64, wn = (wave & 1) * 64;
  int c0 = wave * 128 + lane;          // chunk ids for this wave's 2 issues
  int c1 = c0 + 64;
  int r0 = c0 >> 2, k80 = (c0 & 3) * 8;
  int r1 = c1 >> 2, k81 = (c1 & 3) * 8;
  u16* dA0 = lA + (wave * 2 + 0) * 512;   // wave-uniform LDS dest bases
  u16* dA1 = lA + (wave * 2 + 1) * 512;
  u16* dB0 = lB + (wave * 2 + 0) * 512;
  u16* dB1 = lB + (wave * 2 + 1) * 512;
  const u16* Ab = A + arow0 * LATENT;
  const u16* Bb = B + brow0 * LATENT;
  for (int k0 = 0; k0 < LATENT; k0 += 32) {
    gload16(Ab + (size_t)r0 * LATENT + k0 + k80, dA0);
    gload16(Ab + (size_t)r1 * LATENT + k0 + k81, dA1);
    gload16(Bb + (size_t)r0 * LATENT + k0 + k80, dB0);
    gload16(Bb + (size_t)r1 * LATENT + k0 + k81, dB1);
    __syncthreads();
    bf16x8 af[4], bv[4];
#pragma unroll
    for (int f = 0; f < 4; f++) {
      af[f] = *(const bf16x8*)(lA + (wm + f * 16 + l16) * 32 + q * 8);
      bv[f] = *(const bf16x8*)(lB + (wn + f * 16 + l16) * 32 + q * 8);
    }
#pragma unroll
    for (int fm = 0; fm < 4; fm++)
#pragma unroll
      for (int fn = 0; fn < 4; fn++)
        acc[fm][fn] = mfma_bf16(af[fm], bv[fn], acc[fm][fn]);
    __syncthreads();
  }
}

// ---------------- GEMM 1: out = x @ Mt^T  (+ xx*sc + cc), writes sub_out/sup_out
__global__ __launch_bounds__(256) void k_gemm_out(const u16* __restrict__ A,
    const u16* __restrict__ B, const float* __restrict__ xx,
    const float* __restrict__ sc, const float* __restrict__ cc,
    float* __restrict__ out) {
  __shared__ __align__(16) u16 lA[128 * 32];
  __shared__ __align__(16) u16 lB[128 * 32];
  floatx4 acc[4][4] = {};
  size_t arow0 = (size_t)blockIdx.x * 128;
  size_t brow0 = (size_t)blockIdx.y * 128;
  gemm_core(A, B, lA, lB, arow0, brow0, acc);

  int lane = threadIdx.x & 63, wave = threadIdx.x >> 6;
  int l16 = lane & 15, q = lane >> 4;
  int wm = (wave >> 1) * 64, wn = (wave & 1) * 64;
  int colb = (int)brow0 + wn + l16;
  float scv[4], ccv[4];
#pragma unroll
  for (int fn = 0; fn < 4; fn++) {
    int c = colb + fn * 16;
    bool ok = c < 400;
    scv[fn] = ok ? sc[c] : 0.f;
    ccv[fn] = ok ? cc[c] : 0.f;
  }
#pragma unroll
  for (int fm = 0; fm < 4; fm++) {
#pragma unroll
    for (int r = 0; r < 4; r++) {
      int row = (int)arow0 + wm + fm * 16 + q * 4 + r;
      float xv = xx[row];
#pragma unroll
      for (int fn = 0; fn < 4; fn++) {
        int c = colb + fn * 16;
        if (c < 400) {
          float v = acc[fm][fn][r] + xv * scv[fn] + ccv[fn];
          size_t idx = (c < 200) ? (SUP_OFF + (size_t)row * NOUT + c)
                                 : ((size_t)row * NOUT + (c - 200));
          out[idx] = v;
        }
      }
    }
  }
}

// ---------------- GEMM 2: dist mins over [x; sup] vs sub. No C write.
__global__ __launch_bounds__(256) void k_gemm_min(const u16* __restrict__ A,
    const u16* __restrict__ B, const float* __restrict__ xx,
    const float* __restrict__ yy, unsigned int* __restrict__ rowmin,
    unsigned int* __restrict__ colmin_x, unsigned int* __restrict__ colmin_sup) {
  __shared__ __align__(16) u16 lA[128 * 32];
  __shared__ __align__(16) u16 lB[128 * 32];
  floatx4 acc[4][4] = {};
  size_t arow0 = (size_t)blockIdx.x * 128;
  size_t brow0 = (size_t)blockIdx.y * 128;
  gemm_core(A, B, lA, lB, arow0, brow0, acc);

  int lane = threadIdx.x & 63, wave = threadIdx.x >> 6;
  int l16 = lane & 15, q = lane >> 4;
  int wm = (wave >> 1) * 64, wn = (wave & 1) * 64;
  int colb = (int)brow0 + wn + l16;
  float yv[4];
#pragma unroll
  for (int fn = 0; fn < 4; fn++) yv[fn] = yy[colb + fn * 16];
  float cmin[4] = {3.4e38f, 3.4e38f, 3.4e38f, 3.4e38f};
#pragma unroll
  for (int fm = 0; fm < 4; fm++) {
#pragma unroll
    for (int r = 0; r < 4; r++) {
      int row = (int)arow0 + wm + fm * 16 + q * 4 + r;
      float xv = xx[row];
      float rmin = 3.4e38f;
#pragma unroll
      for (int fn = 0; fn < 4; fn++) {
        float d = xv - 2.0f * acc[fm][fn][r] + yv[fn];
        rmin = fminf(rmin, d);
        cmin[fn] = fminf(cmin[fn], d);
      }
      for (int off = 1; off < 16; off <<= 1) rmin = fminf(rmin, __shfl_xor(rmin, off));
      if (l16 == 0) atomicMin(rowmin + row, __float_as_uint(rmin));
    }
  }
  unsigned int* cdst = (blockIdx.x < 256) ? colmin_x : colmin_sup;
#pragma unroll
  for (int fn = 0; fn < 4; fn++) {
    float v = cmin[fn];
    v = fminf(v, __shfl_xor(v, 16));
    v = fminf(v, __shfl_xor(v, 32));
    if (q == 0) atomicMin(cdst + colb + fn * 16, __float_as_uint(v));
  }
}

// ---------------- final: means of mins -> r1,r2,r3,r4
__device__ __forceinline__ float block_sum(float v) {
  __shared__ float red[4];
  __syncthreads();
  for (int off = 32; off; off >>= 1) v += __shfl_down(v, off);
  if ((threadIdx.x & 63) == 0) red[threadIdx.x >> 6] = v;
  __syncthreads();
  return red[0] + red[1] + red[2] + red[3];
}

__global__ __launch_bounds__(256) void k_final(const unsigned int* __restrict__ rowmin,
    const unsigned int* __restrict__ colmin_x, const unsigned int* __restrict__ colmin_sup,
    float* __restrict__ out4) {
  int t = threadIdx.x;
  float s;
  s = 0.f; for (int i = t; i < NSUB; i += 256) s += __uint_as_float(colmin_x[i]);
  float r1 = block_sum(s) * (1.0f / NSUB);
  s = 0.f; for (int i = t; i < BATCH; i += 256) s += __uint_as_float(rowmin[i]);
  float r2 = block_sum(s) * (1.0f / BATCH);
  s = 0.f; for (int i = t; i < NSUP; i += 256) s += __uint_as_float(rowmin[BATCH + i]);
  float r3 = block_sum(s) * (1.0f / NSUP);
  s = 0.f; for (int i = t; i < NSUB; i += 256) s += __uint_as_float(colmin_sup[i]);
  float r4 = block_sum(s) * (1.0f / NSUB);
  if (t == 0) { out4[0] = r1; out4[1] = r2; out4[2] = r3; out4[3] = r4; }
}

extern "C" void kernel_launch(void* const* d_in, const int* in_sizes, int n_in,
                              void* d_out, int out_size, void* d_ws, size_t ws_size,
                              hipStream_t stream) {
  const float* x   = (const float*)d_in[0];
  const float* sup = (const float*)d_in[1];
  const float* sub = (const float*)d_in[2];
  const float* W1  = (const float*)d_in[3];
  const float* b1  = (const float*)d_in[4];
  const float* W2  = (const float*)d_in[5];
  const float* b2  = (const float*)d_in[6];
  float* out = (float*)d_out;

  char* p = (char*)d_ws;
  u16* xs    = (u16*)p;            p += (size_t)M_EXT * LATENT * 2;   // x + sup, bf16
  u16* subs  = (u16*)p;            p += (size_t)NSUB * LATENT * 2;    // sub, bf16
  u16* Mt    = (u16*)p;            p += (size_t)512 * LATENT * 2;     // fused weights (rows 400..511 zero)
  float* xx  = (float*)p;          p += (size_t)M_EXT * 4;            // ||x||^2 then ||sup||^2
  float* yys = (float*)p;          p += (size_t)NSUB * 4;             // ||sub||^2
  float* sc  = (float*)p;          p += 512 * 4;
  float* cc  = (float*)p;          p += 512 * 4;
  unsigned int* rowmin = (unsigned int*)p; p += (size_t)M_EXT * 4;
  unsigned int* colx   = (unsigned int*)p; p += (size_t)NSUB * 4;
  unsigned int* colsup = (unsigned int*)p; p += (size_t)NSUB * 4;

  hipLaunchKernelGGL(k_convert, dim3(BATCH / 4), dim3(256), 0, stream, x,   xs, xx);
  hipLaunchKernelGGL(k_convert, dim3(NSUP / 4),  dim3(256), 0, stream, sup, xs + (size_t)BATCH * LATENT, xx + BATCH);
  hipLaunchKernelGGL(k_convert, dim3(NSUB / 4),  dim3(256), 0, stream, sub, subs, yys);
  hipLaunchKernelGGL(k_wprep, dim3(2), dim3(256), 0, stream, W1, b1, W2, b2, xx + BATCH, yys, sc, cc);
  hipLaunchKernelGGL(k_mt, dim3(2, 128), dim3(256), 0, stream, sup, sub, W1, W2, Mt);
  int initn = M_EXT + 2 * NSUB;
  hipLaunchKernelGGL(k_init, dim3((initn + 255) / 256), dim3(256), 0, stream, rowmin, initn);
  hipLaunchKernelGGL(k_gemm_out, dim3(BATCH / 128, 4), dim3(256), 0, stream, xs, Mt, xx, sc, cc, out);
  hipLaunchKernelGGL(k_gemm_min, dim3(M_EXT / 128, 8), dim3(256), 0, stream, xs, subs, xx, yys, rowmin, colx, colsup);
  hipLaunchKernelGGL(k_final, dim3(1), dim3(256), 0, stream, rowmin, colx, colsup, out + 2 * SUP_OFF);
}

// Round 2
// 355.689 us; speedup vs baseline: 1.0387x; 1.0387x over previous
//
#include <hip/hip_runtime.h>
#include <stdint.h>

#define BATCH   32768
#define NSUP    256
#define NSUB    1024
#define LATENT  512
#define NOUT    200
#define M_EXT   (BATCH + NSUP)          // 33024 = 258*128
#define SUP_OFF ((size_t)BATCH * NOUT)  // sup_out offset in d_out

typedef unsigned short u16;
typedef __attribute__((ext_vector_type(8))) __bf16 bf16x8;
typedef __attribute__((ext_vector_type(4))) float  floatx4;

typedef const __attribute__((address_space(1))) void* gptr_t;
typedef __attribute__((address_space(3))) void* sptr_t;

__device__ __forceinline__ void gload16(const void* g, void* l) {
  __builtin_amdgcn_global_load_lds((gptr_t)g, (sptr_t)l, 16, 0, 0);
}

__device__ __forceinline__ floatx4 mfma_bf16(bf16x8 a, bf16x8 b, floatx4 c) {
  return __builtin_amdgcn_mfma_f32_16x16x32_bf16(a, b, c, 0, 0, 0);
}

__device__ __forceinline__ u16 f2bf(float f) {
  unsigned int u = __float_as_uint(f);
  u += 0x7FFFu + ((u >> 16) & 1u);   // RNE; inputs finite
  return (u16)(u >> 16);
}

// ---------------- all three fp32->bf16 conversions + row norms in one kernel
__global__ __launch_bounds__(256) void k_convert_all(const float* __restrict__ x,
    const float* __restrict__ sup, const float* __restrict__ sub,
    u16* __restrict__ xs, u16* __restrict__ subs,
    float* __restrict__ xx, float* __restrict__ yys) {
  int row  = blockIdx.x * 4 + (threadIdx.x >> 6);
  int lane = threadIdx.x & 63;
  const float* src; u16* dst; float* nrm;
  if (row < BATCH)             { src = x   + (size_t)row * LATENT;              dst = xs   + (size_t)row * LATENT; nrm = xx + row; }
  else if (row < BATCH + NSUP) { src = sup + (size_t)(row - BATCH) * LATENT;    dst = xs   + (size_t)row * LATENT; nrm = xx + row; }
  else { int r = row - BATCH - NSUP; src = sub + (size_t)r * LATENT;            dst = subs + (size_t)r * LATENT;   nrm = yys + r; }
  const float* s = src + lane * 8;
  float4 v0 = ((const float4*)s)[0];
  float4 v1 = ((const float4*)s)[1];
  float ss = v0.x*v0.x + v0.y*v0.y + v0.z*v0.z + v0.w*v0.w
           + v1.x*v1.x + v1.y*v1.y + v1.z*v1.z + v1.w*v1.w;
  uint4 o;
  o.x = (unsigned)f2bf(v0.x) | ((unsigned)f2bf(v0.y) << 16);
  o.y = (unsigned)f2bf(v0.z) | ((unsigned)f2bf(v0.w) << 16);
  o.z = (unsigned)f2bf(v1.x) | ((unsigned)f2bf(v1.y) << 16);
  o.w = (unsigned)f2bf(v1.z) | ((unsigned)f2bf(v1.w) << 16);
  *((uint4*)(dst + lane * 8)) = o;
  for (int off = 32; off; off >>= 1) ss += __shfl_down(ss, off);
  if (lane == 0) *nrm = ss;
}

// ---------------- init min arrays (+inf) AND per-output constants, one kernel
// blocks [0,137): init 35072 uints; blocks [137,139): wprep for 400 outputs
__global__ __launch_bounds__(256) void k_prep(const float* __restrict__ W1,
    const float* __restrict__ b1, const float* __restrict__ W2,
    const float* __restrict__ b2, const float* __restrict__ yy_sup,
    const float* __restrict__ yy_sub, float* __restrict__ sc,
    float* __restrict__ cc, unsigned int* __restrict__ minbuf, int initn) {
  int bx = blockIdx.x;
  if (bx < 137) {
    int i = bx * 256 + threadIdx.x;
    if (i < initn) minbuf[i] = 0x7F800000u;
    return;
  }
  int o = (bx - 137) * 256 + threadIdx.x;
  if (o >= 400) return;
  float s = 0.f, c = 0.f;
  if (o < 200) {
    for (int j = 0; j < NSUP; j++) { float w = W1[o*NSUP + j]; s += w; c += w * yy_sup[j]; }
    c += b1[o];
  } else {
    int oo = o - 200;
    for (int j = 0; j < NSUB; j++) { float w = W2[oo*NSUB + j]; s += w; c += w * yy_sub[j]; }
    c += b2[oo];
  }
  sc[o] = s; cc[o] = c;
}

// ---------------- Mt[o][k] = -2 * sum_j W[o,j] * P[j,k]   (bf16, rows 400..511 zero)
__global__ __launch_bounds__(256) void k_mt(const float* __restrict__ sup,
    const float* __restrict__ sub, const float* __restrict__ W1,
    const float* __restrict__ W2, u16* __restrict__ Mt) {
  __shared__ float lw[4 * 1024];
  int k  = blockIdx.x * 256 + threadIdx.x;
  int o0 = blockIdx.y * 4;
  if (o0 >= 400) {
    for (int oo = 0; oo < 4; oo++) Mt[(size_t)(o0 + oo) * LATENT + k] = 0;
    return;
  }
  const float* P; const float* W; int n, ow;
  if (o0 < 200) { P = sup; W = W1; n = NSUP;  ow = o0; }
  else          { P = sub; W = W2; n = NSUB;  ow = o0 - 200; }
  for (int idx = threadIdx.x; idx < 4 * n; idx += 256) {
    int oo = idx / n, j = idx & (n - 1);
    lw[oo * 1024 + j] = W[(size_t)(ow + oo) * n + j];
  }
  __syncthreads();
  float a0 = 0, a1 = 0, a2 = 0, a3 = 0;
  for (int j = 0; j < n; j++) {
    float p = P[(size_t)j * LATENT + k];
    a0 += p * lw[j];
    a1 += p * lw[1024 + j];
    a2 += p * lw[2048 + j];
    a3 += p * lw[3072 + j];
  }
  Mt[(size_t)(o0 + 0) * LATENT + k] = f2bf(-2.f * a0);
  Mt[(size_t)(o0 + 1) * LATENT + k] = f2bf(-2.f * a1);
  Mt[(size_t)(o0 + 2) * LATENT + k] = f2bf(-2.f * a2);
  Mt[(size_t)(o0 + 3) * LATENT + k] = f2bf(-2.f * a3);
}

// ---------------- merged GEMM: C = A(33024x512) @ Bext(1536x512)^T
// colblocks 0..3  -> Mt columns (classifier heads, write out)
// colblocks 4..11 -> subs columns (distance min-reductions)
// LDS: 128x64 bf16 tiles, XOR-8 swizzle: chunk(row,q) -> slot row*8 + (q^(row&7))
__global__ __launch_bounds__(256) void k_gemm(const u16* __restrict__ A,
    const u16* __restrict__ Mt, const u16* __restrict__ subs,
    const float* __restrict__ xx, const float* __restrict__ yy,
    const float* __restrict__ sc, const float* __restrict__ cc,
    float* __restrict__ out, unsigned int* __restrict__ rowmin,
    unsigned int* __restrict__ colmin_x, unsigned int* __restrict__ colmin_sup) {
  __shared__ __align__(16) u16 lA[128 * 64];
  __shared__ __align__(16) u16 lB[128 * 64];
  int cb = blockIdx.x;
  size_t arow0 = (size_t)blockIdx.y * 128;
  const u16* B = (cb < 4) ? (Mt + (size_t)cb * 128 * LATENT)
                          : (subs + (size_t)(cb - 4) * 128 * LATENT);
  floatx4 acc[4][4] = {};
  int t = threadIdx.x, wave = t >> 6, lane = t & 63;
  int l16 = lane & 15, qq = lane >> 4;
  int wm = (wave >> 1) * 64, wn = (wave & 1) * 64;

  // staging: 1024 chunks/tile, 4 issues/thread; slot s=i*256+t holds
  // row=s>>3, k-chunk q=(s&7)^(row&7). For s&7==lane&7, row&7==lane>>3.
  int sq = (lane & 7) ^ (lane >> 3);
  const u16* Ab = A + arow0 * LATENT;
  int soff[4]; u16 *dA[4], *dB[4];
#pragma unroll
  for (int i = 0; i < 4; i++) {
    int s = i * 256 + t;
    soff[i] = (s >> 3) * LATENT + sq * 8;
    int sbase = (i * 256 + wave * 64) * 8;   // u16 units (slot*8)
    dA[i] = lA + sbase; dB[i] = lB + sbase;
  }

  for (int k0 = 0; k0 < LATENT; k0 += 64) {
#pragma unroll
    for (int i = 0; i < 4; i++) gload16(Ab + soff[i] + k0, dA[i]);
#pragma unroll
    for (int i = 0; i < 4; i++) gload16(B  + soff[i] + k0, dB[i]);
    __syncthreads();
#pragma unroll
    for (int ks = 0; ks < 2; ks++) {
      bf16x8 af[4], bv[4];
      int sw = ((ks * 4 + qq) ^ (l16 & 7)) * 8;
#pragma unroll
      for (int f = 0; f < 4; f++) {
        af[f] = *(const bf16x8*)(lA + (wm + f * 16 + l16) * 64 + sw);
        bv[f] = *(const bf16x8*)(lB + (wn + f * 16 + l16) * 64 + sw);
      }
#pragma unroll
      for (int fm = 0; fm < 4; fm++)
#pragma unroll
        for (int fn = 0; fn < 4; fn++)
          acc[fm][fn] = mfma_bf16(af[fm], bv[fn], acc[fm][fn]);
    }
    __syncthreads();
  }

  if (cb < 4) {
    // classifier-head epilogue: out = acc + xx*sc + cc
    if (arow0 >= BATCH) return;   // sup rows don't produce outputs
    int colb = cb * 128 + wn + l16;
    float scv[4], ccv[4];
#pragma unroll
    for (int fn = 0; fn < 4; fn++) {
      int c = colb + fn * 16;
      bool ok = c < 400;
      scv[fn] = ok ? sc[c] : 0.f;
      ccv[fn] = ok ? cc[c] : 0.f;
    }
#pragma unroll
    for (int fm = 0; fm < 4; fm++) {
#pragma unroll
      for (int r = 0; r < 4; r++) {
        int row = (int)arow0 + wm + fm * 16 + qq * 4 + r;
        float xv = xx[row];
#pragma unroll
        for (int fn = 0; fn < 4; fn++) {
          int c = colb + fn * 16;
          if (c < 400) {
            float v = acc[fm][fn][r] + xv * scv[fn] + ccv[fn];
            size_t idx = (c < 200) ? (SUP_OFF + (size_t)row * NOUT + c)
                                   : ((size_t)row * NOUT + (c - 200));
            out[idx] = v;
          }
        }
      }
    }
  } else {
    // distance-min epilogue: d = xx - 2*acc + yy
    int colb = (cb - 4) * 128 + wn + l16;
    float yv[4];
#pragma unroll
    for (int fn = 0; fn < 4; fn++) yv[fn] = yy[colb + fn * 16];
    float cmin[4] = {3.4e38f, 3.4e38f, 3.4e38f, 3.4e38f};
#pragma unroll
    for (int fm = 0; fm < 4; fm++) {
#pragma unroll
      for (int r = 0; r < 4; r++) {
        int row = (int)arow0 + wm + fm * 16 + qq * 4 + r;
        float xv = xx[row];
        float rmin = 3.4e38f;
#pragma unroll
        for (int fn = 0; fn < 4; fn++) {
          float d = xv - 2.0f * acc[fm][fn][r] + yv[fn];
          rmin = fminf(rmin, d);
          cmin[fn] = fminf(cmin[fn], d);
        }
        for (int off = 1; off < 16; off <<= 1) rmin = fminf(rmin, __shfl_xor(rmin, off));
        if (l16 == 0) atomicMin(rowmin + row, __float_as_uint(rmin));
      }
    }
    unsigned int* cdst = (blockIdx.y < 256) ? colmin_x : colmin_sup;
#pragma unroll
    for (int fn = 0; fn < 4; fn++) {
      float v = cmin[fn];
      v = fminf(v, __shfl_xor(v, 16));
      v = fminf(v, __shfl_xor(v, 32));
      if (qq == 0) atomicMin(cdst + colb + fn * 16, __float_as_uint(v));
    }
  }
}

// ---------------- final: means of mins -> r1,r2,r3,r4
__device__ __forceinline__ float block_sum(float v) {
  __shared__ float red[4];
  __syncthreads();
  for (int off = 32; off; off >>= 1) v += __shfl_down(v, off);
  if ((threadIdx.x & 63) == 0) red[threadIdx.x >> 6] = v;
  __syncthreads();
  return red[0] + red[1] + red[2] + red[3];
}

__global__ __launch_bounds__(256) void k_final(const unsigned int* __restrict__ rowmin,
    const unsigned int* __restrict__ colmin_x, const unsigned int* __restrict__ colmin_sup,
    float* __restrict__ out4) {
  int t = threadIdx.x;
  float s;
  s = 0.f; for (int i = t; i < NSUB; i += 256) s += __uint_as_float(colmin_x[i]);
  float r1 = block_sum(s) * (1.0f / NSUB);
  s = 0.f; for (int i = t; i < BATCH; i += 256) s += __uint_as_float(rowmin[i]);
  float r2 = block_sum(s) * (1.0f / BATCH);
  s = 0.f; for (int i = t; i < NSUP; i += 256) s += __uint_as_float(rowmin[BATCH + i]);
  float r3 = block_sum(s) * (1.0f / NSUP);
  s = 0.f; for (int i = t; i < NSUB; i += 256) s += __uint_as_float(colmin_sup[i]);
  float r4 = block_sum(s) * (1.0f / NSUB);
  if (t == 0) { out4[0] = r1; out4[1] = r2; out4[2] = r3; out4[3] = r4; }
}

extern "C" void kernel_launch(void* const* d_in, const int* in_sizes, int n_in,
                              void* d_out, int out_size, void* d_ws, size_t ws_size,
                              hipStream_t stream) {
  const float* x   = (const float*)d_in[0];
  const float* sup = (const float*)d_in[1];
  const float* sub = (const float*)d_in[2];
  const float* W1  = (const float*)d_in[3];
  const float* b1  = (const float*)d_in[4];
  const float* W2  = (const float*)d_in[5];
  const float* b2  = (const float*)d_in[6];
  float* out = (float*)d_out;

  char* p = (char*)d_ws;
  u16* xs    = (u16*)p;            p += (size_t)M_EXT * LATENT * 2;   // x + sup, bf16
  u16* subs  = (u16*)p;            p += (size_t)NSUB * LATENT * 2;    // sub, bf16
  u16* Mt    = (u16*)p;            p += (size_t)512 * LATENT * 2;     // fused weights (rows 400..511 zero)
  float* xx  = (float*)p;          p += (size_t)M_EXT * 4;            // ||x||^2 then ||sup||^2
  float* yys = (float*)p;          p += (size_t)NSUB * 4;             // ||sub||^2
  float* sc  = (float*)p;          p += 512 * 4;
  float* cc  = (float*)p;          p += 512 * 4;
  unsigned int* rowmin = (unsigned int*)p; p += (size_t)M_EXT * 4;    // keep these three
  unsigned int* colx   = (unsigned int*)p; p += (size_t)NSUB * 4;     // contiguous for
  unsigned int* colsup = (unsigned int*)p; p += (size_t)NSUB * 4;     // one-shot init

  int initn = M_EXT + 2 * NSUB;   // 35072

  hipLaunchKernelGGL(k_convert_all, dim3((BATCH + NSUP + NSUB) / 4), dim3(256), 0, stream,
                     x, sup, sub, xs, subs, xx, yys);
  hipLaunchKernelGGL(k_mt, dim3(2, 128), dim3(256), 0, stream, sup, sub, W1, W2, Mt);
  hipLaunchKernelGGL(k_prep, dim3(139), dim3(256), 0, stream,
                     W1, b1, W2, b2, xx + BATCH, yys, sc, cc, rowmin, initn);
  hipLaunchKernelGGL(k_gemm, dim3(12, 258), dim3(256), 0, stream,
                     xs, Mt, subs, xx, yys, sc, cc, out, rowmin, colx, colsup);
  hipLaunchKernelGGL(k_final, dim3(1), dim3(256), 0, stream, rowmin, colx, colsup, out + 2 * SUP_OFF);
}

// Round 3
// 325.789 us; speedup vs baseline: 1.1340x; 1.0918x over previous
//
#include <hip/hip_runtime.h>
#include <stdint.h>

#define BATCH   32768
#define NSUP    256
#define NSUB    1024
#define LATENT  512
#define NOUT    200
#define SUP_OFF ((size_t)BATCH * NOUT)  // sup_out offset in d_out

typedef unsigned short u16;
typedef __attribute__((ext_vector_type(8))) __bf16 bf16x8;
typedef __attribute__((ext_vector_type(4))) float  floatx4;

typedef const __attribute__((address_space(1))) void* gptr_t;
typedef __attribute__((address_space(3))) void* sptr_t;

__device__ __forceinline__ void gload16(const void* g, void* l) {
  __builtin_amdgcn_global_load_lds((gptr_t)g, (sptr_t)l, 16, 0, 0);
}

__device__ __forceinline__ floatx4 mfma_bf16(bf16x8 a, bf16x8 b, floatx4 c) {
  return __builtin_amdgcn_mfma_f32_16x16x32_bf16(a, b, c, 0, 0, 0);
}

__device__ __forceinline__ u16 f2bf(float f) {
  unsigned int u = __float_as_uint(f);
  u += 0x7FFFu + ((u >> 16) & 1u);   // RNE; inputs finite
  return (u16)(u >> 16);
}

// ---------------- sup+sub fp32->bf16 + row norms (1280 rows total)
__global__ __launch_bounds__(256) void k_convert_small(const float* __restrict__ sup,
    const float* __restrict__ sub, u16* __restrict__ sups, u16* __restrict__ subs,
    float* __restrict__ xxsup, float* __restrict__ yys) {
  int row  = blockIdx.x * 4 + (threadIdx.x >> 6);
  int lane = threadIdx.x & 63;
  const float* src; u16* dst; float* nrm;
  if (row < NSUP) { src = sup + (size_t)row * LATENT; dst = sups + (size_t)row * LATENT; nrm = xxsup + row; }
  else { int r = row - NSUP; src = sub + (size_t)r * LATENT; dst = subs + (size_t)r * LATENT; nrm = yys + r; }
  const float* s = src + lane * 8;
  float4 v0 = ((const float4*)s)[0];
  float4 v1 = ((const float4*)s)[1];
  float ss = v0.x*v0.x + v0.y*v0.y + v0.z*v0.z + v0.w*v0.w
           + v1.x*v1.x + v1.y*v1.y + v1.z*v1.z + v1.w*v1.w;
  uint4 o;
  o.x = (unsigned)f2bf(v0.x) | ((unsigned)f2bf(v0.y) << 16);
  o.y = (unsigned)f2bf(v0.z) | ((unsigned)f2bf(v0.w) << 16);
  o.z = (unsigned)f2bf(v1.x) | ((unsigned)f2bf(v1.y) << 16);
  o.w = (unsigned)f2bf(v1.z) | ((unsigned)f2bf(v1.w) << 16);
  *((uint4*)(dst + lane * 8)) = o;
  for (int off = 32; off; off >>= 1) ss += __shfl_down(ss, off);
  if (lane == 0) *nrm = ss;
}

// ---------------- Mt[o][k] = -2 * sum_j W[o,j] * P[j,k]  (8 outs/block; rows 400..511 zero)
__global__ __launch_bounds__(256) void k_mt8(const float* __restrict__ sup,
    const float* __restrict__ sub, const float* __restrict__ W1,
    const float* __restrict__ W2, u16* __restrict__ Mt) {
  __shared__ float lw[8 * 1024];
  int k  = blockIdx.x * 256 + threadIdx.x;
  int o0 = blockIdx.y * 8;
  if (o0 >= 400) {
    for (int oo = 0; oo < 8; oo++) Mt[(size_t)(o0 + oo) * LATENT + k] = 0;
    return;
  }
  const float* P; const float* W; int n, ow;
  if (o0 < 200) { P = sup; W = W1; n = NSUP;  ow = o0; }
  else          { P = sub; W = W2; n = NSUB;  ow = o0 - 200; }
  for (int idx = threadIdx.x; idx < 8 * n; idx += 256) {
    int oo = idx / n, j = idx & (n - 1);
    lw[oo * 1024 + j] = W[(size_t)(ow + oo) * n + j];
  }
  __syncthreads();
  float a[8] = {};
  for (int j = 0; j < n; j++) {
    float pv = P[(size_t)j * LATENT + k];
#pragma unroll
    for (int oo = 0; oo < 8; oo++) a[oo] += pv * lw[oo * 1024 + j];
  }
#pragma unroll
  for (int oo = 0; oo < 8; oo++) Mt[(size_t)(o0 + oo) * LATENT + k] = f2bf(-2.f * a[oo]);
}

// ---------------- init min arrays (+inf), wprep constants, zero r-slots
__global__ __launch_bounds__(256) void k_prep(const float* __restrict__ W1,
    const float* __restrict__ b1, const float* __restrict__ W2,
    const float* __restrict__ b2, const float* __restrict__ yy_sup,
    const float* __restrict__ yy_sub, float* __restrict__ sc,
    float* __restrict__ cc, unsigned int* __restrict__ minbuf, int initn,
    float* __restrict__ out4) {
  int bx = blockIdx.x;
  if (bx < 137) {
    int i = bx * 256 + threadIdx.x;
    if (i < initn) minbuf[i] = 0x7F800000u;
    return;
  }
  if (bx == 137 && threadIdx.x < 4) out4[threadIdx.x] = 0.f;
  int o = (bx - 137) * 256 + threadIdx.x;
  if (o >= 400) return;
  float s = 0.f, c = 0.f;
  if (o < 200) {
    for (int j = 0; j < NSUP; j++) { float w = W1[o*NSUP + j]; s += w; c += w * yy_sup[j]; }
    c += b1[o];
  } else {
    int oo = o - 200;
    for (int j = 0; j < NSUB; j++) { float w = W2[oo*NSUB + j]; s += w; c += w * yy_sub[j]; }
    c += b2[oo];
  }
  sc[o] = s; cc[o] = c;
}

// ---------------- THE kernel: A(x,64 rows)->LDS once (fused cvt+norm), B from L2.
// Barrier-free K-loop. Grid 512 = 2 blocks/CU exactly.
// Bext = [Mt(512 rows) ; subs(1024 rows)], row-major K=512 bf16.
__global__ __launch_bounds__(256, 2) void k_gemm_x(const float* __restrict__ x,
    const u16* __restrict__ Bext, const float* __restrict__ yys,
    const float* __restrict__ sc, const float* __restrict__ cc,
    float* __restrict__ out, unsigned int* __restrict__ rowmin,
    unsigned int* __restrict__ colx) {
  __shared__ __align__(16) u16 lA[64 * 512];   // 64 KB, 16B-chunk XOR-8 swizzle
  __shared__ float lxx[64];
  int t = threadIdx.x, wave = t >> 6, lane = t & 63;
  int l16 = lane & 15, qq = lane >> 4;
  size_t arow0 = (size_t)blockIdx.x * 64;

  // ---- stage A: fp32 load -> bf16 LDS (swizzled) + row sum-of-squares
  const float* Ab = x + arow0 * LATENT;
#pragma unroll
  for (int i = 0; i < 16; i++) {
    int row = i * 4 + wave;                 // wave-uniform row, full row per iter
    const float* s = Ab + (size_t)row * LATENT + lane * 8;
    float4 v0 = ((const float4*)s)[0];
    float4 v1 = ((const float4*)s)[1];
    float ss = v0.x*v0.x + v0.y*v0.y + v0.z*v0.z + v0.w*v0.w
             + v1.x*v1.x + v1.y*v1.y + v1.z*v1.z + v1.w*v1.w;
    uint4 o;
    o.x = (unsigned)f2bf(v0.x) | ((unsigned)f2bf(v0.y) << 16);
    o.y = (unsigned)f2bf(v0.z) | ((unsigned)f2bf(v0.w) << 16);
    o.z = (unsigned)f2bf(v1.x) | ((unsigned)f2bf(v1.y) << 16);
    o.w = (unsigned)f2bf(v1.z) | ((unsigned)f2bf(v1.w) << 16);
    *((uint4*)(lA + ((row * 64) + (lane ^ (row & 7))) * 8)) = o;
    for (int off = 32; off; off >>= 1) ss += __shfl_down(ss, off);
    if (lane == 0) lxx[row] = ss;
  }
  __syncthreads();   // the ONLY barrier

  int wn = wave * 32;
  float xv[4][4];
#pragma unroll
  for (int mf = 0; mf < 4; mf++)
#pragma unroll
    for (int r = 0; r < 4; r++) xv[mf][r] = lxx[mf * 16 + qq * 4 + r];
  float rmreg[4][4];
#pragma unroll
  for (int mf = 0; mf < 4; mf++)
#pragma unroll
    for (int r = 0; r < 4; r++) rmreg[mf][r] = 3.4e38f;

#pragma unroll 1
  for (int p = 0; p < 6; p++) {            // 6 col-pairs of 256 cols
    floatx4 acc[2][4][2] = {};
    const u16* B0 = Bext + (size_t)(p * 256 + wn) * LATENT;
#pragma unroll 2
    for (int k0 = 0; k0 < LATENT; k0 += 64) {
      bf16x8 a[4][2], bv[2][2][2];
#pragma unroll
      for (int mf = 0; mf < 4; mf++)
#pragma unroll
        for (int ks = 0; ks < 2; ks++) {
          int row = mf * 16 + l16;
          int kc = (k0 >> 3) + ks * 4 + qq;
          a[mf][ks] = *(const bf16x8*)(lA + ((row * 64) + (kc ^ (row & 7))) * 8);
        }
#pragma unroll
      for (int h = 0; h < 2; h++)
#pragma unroll
        for (int nf = 0; nf < 2; nf++)
#pragma unroll
          for (int ks = 0; ks < 2; ks++)
            bv[h][nf][ks] = *(const bf16x8*)(B0 + (size_t)(h * 128 + nf * 16 + l16) * LATENT
                                                + k0 + ks * 32 + qq * 8);
#pragma unroll
      for (int h = 0; h < 2; h++)
#pragma unroll
        for (int mf = 0; mf < 4; mf++)
#pragma unroll
          for (int nf = 0; nf < 2; nf++)
#pragma unroll
            for (int ks = 0; ks < 2; ks++)
              acc[h][mf][nf] = mfma_bf16(a[mf][ks], bv[h][nf][ks], acc[h][mf][nf]);
    }
    if (p < 2) {
      // classifier-head epilogue: out = acc + xx*sc + cc (cols p*256..+255, valid<400)
#pragma unroll
      for (int h = 0; h < 2; h++) {
        int colbase = p * 256 + h * 128 + wn;
#pragma unroll
        for (int nf = 0; nf < 2; nf++) {
          int c = colbase + nf * 16 + l16;
          if (c < 400) {
            float scv = sc[c], ccv = cc[c];
#pragma unroll
            for (int mf = 0; mf < 4; mf++)
#pragma unroll
              for (int r = 0; r < 4; r++) {
                size_t row = arow0 + mf * 16 + qq * 4 + r;
                float v = acc[h][mf][nf][r] + xv[mf][r] * scv + ccv;
                size_t idx = (c < 200) ? (SUP_OFF + row * NOUT + c)
                                       : (row * NOUT + (c - 200));
                out[idx] = v;
              }
          }
        }
      }
    } else {
      // distance-min epilogue (sub cols p*256-512..)
#pragma unroll
      for (int h = 0; h < 2; h++) {
        int colbase = p * 256 + h * 128 + wn - 512;
#pragma unroll
        for (int nf = 0; nf < 2; nf++) {
          int cs = colbase + nf * 16 + l16;
          float yv = yys[cs];
          float cmin = 3.4e38f;
#pragma unroll
          for (int mf = 0; mf < 4; mf++)
#pragma unroll
            for (int r = 0; r < 4; r++) {
              float d = xv[mf][r] - 2.0f * acc[h][mf][nf][r] + yv;
              rmreg[mf][r] = fminf(rmreg[mf][r], d);
              cmin = fminf(cmin, d);
            }
          cmin = fminf(cmin, __shfl_xor(cmin, 16));
          cmin = fminf(cmin, __shfl_xor(cmin, 32));
          if (qq == 0) atomicMin(colx + cs, __float_as_uint(cmin));
        }
      }
    }
  }
  // row mins (across the wave's 32 cols; waves/blocks merge via atomics)
#pragma unroll
  for (int mf = 0; mf < 4; mf++)
#pragma unroll
    for (int r = 0; r < 4; r++) {
      float v = rmreg[mf][r];
      v = fminf(v, __shfl_xor(v, 1));
      v = fminf(v, __shfl_xor(v, 2));
      v = fminf(v, __shfl_xor(v, 4));
      v = fminf(v, __shfl_xor(v, 8));
      if (l16 == 0) atomicMin(rowmin + arow0 + mf * 16 + qq * 4 + r, __float_as_uint(v));
    }
}

// ---------------- sup(256) x sub(1024) distances -> rowmin[BATCH..], colsup (r3,r4)
// round-2 staged-MFMA structure (known-correct, zero conflicts); 16 blocks only.
__global__ __launch_bounds__(256) void k_sup(const u16* __restrict__ A,
    const u16* __restrict__ subs, const float* __restrict__ xxsup,
    const float* __restrict__ yys, unsigned int* __restrict__ rowmin,
    unsigned int* __restrict__ colsup) {
  __shared__ __align__(16) u16 lA[128 * 64];
  __shared__ __align__(16) u16 lB[128 * 64];
  int cb = blockIdx.x;
  size_t arow0 = (size_t)blockIdx.y * 128;
  const u16* B = subs + (size_t)cb * 128 * LATENT;
  floatx4 acc[4][4] = {};
  int t = threadIdx.x, wave = t >> 6, lane = t & 63;
  int l16 = lane & 15, qq = lane >> 4;
  int wm = (wave >> 1) * 64, wn = (wave & 1) * 64;

  int sq = (lane & 7) ^ (lane >> 3);
  const u16* Ab = A + arow0 * LATENT;
  int soff[4]; u16 *dA[4], *dB[4];
#pragma unroll
  for (int i = 0; i < 4; i++) {
    int s = i * 256 + t;
    soff[i] = (s >> 3) * LATENT + sq * 8;
    int sbase = (i * 256 + wave * 64) * 8;
    dA[i] = lA + sbase; dB[i] = lB + sbase;
  }
  for (int k0 = 0; k0 < LATENT; k0 += 64) {
#pragma unroll
    for (int i = 0; i < 4; i++) gload16(Ab + soff[i] + k0, dA[i]);
#pragma unroll
    for (int i = 0; i < 4; i++) gload16(B  + soff[i] + k0, dB[i]);
    __syncthreads();
#pragma unroll
    for (int ks = 0; ks < 2; ks++) {
      bf16x8 af[4], bvv[4];
      int sw = ((ks * 4 + qq) ^ (l16 & 7)) * 8;
#pragma unroll
      for (int f = 0; f < 4; f++) {
        af[f]  = *(const bf16x8*)(lA + (wm + f * 16 + l16) * 64 + sw);
        bvv[f] = *(const bf16x8*)(lB + (wn + f * 16 + l16) * 64 + sw);
      }
#pragma unroll
      for (int fm = 0; fm < 4; fm++)
#pragma unroll
        for (int fn = 0; fn < 4; fn++)
          acc[fm][fn] = mfma_bf16(af[fm], bvv[fn], acc[fm][fn]);
    }
    __syncthreads();
  }
  int colb = cb * 128 + wn + l16;
  float yv[4];
#pragma unroll
  for (int fn = 0; fn < 4; fn++) yv[fn] = yys[colb + fn * 16];
  float cmin[4] = {3.4e38f, 3.4e38f, 3.4e38f, 3.4e38f};
#pragma unroll
  for (int fm = 0; fm < 4; fm++) {
#pragma unroll
    for (int r = 0; r < 4; r++) {
      int row = (int)arow0 + wm + fm * 16 + qq * 4 + r;
      float xvv = xxsup[row];
      float rmin = 3.4e38f;
#pragma unroll
      for (int fn = 0; fn < 4; fn++) {
        float d = xvv - 2.0f * acc[fm][fn][r] + yv[fn];
        rmin = fminf(rmin, d);
        cmin[fn] = fminf(cmin[fn], d);
      }
      for (int off = 1; off < 16; off <<= 1) rmin = fminf(rmin, __shfl_xor(rmin, off));
      if (l16 == 0) atomicMin(rowmin + BATCH + row, __float_as_uint(rmin));
    }
  }
#pragma unroll
  for (int fn = 0; fn < 4; fn++) {
    float v = cmin[fn];
    v = fminf(v, __shfl_xor(v, 16));
    v = fminf(v, __shfl_xor(v, 32));
    if (qq == 0) atomicMin(colsup + colb + fn * 16, __float_as_uint(v));
  }
}

// ---------------- parallel means of mins -> r1,r2,r3,r4 (atomicAdd partials)
__global__ __launch_bounds__(256) void k_final2(const unsigned int* __restrict__ rowmin,
    const unsigned int* __restrict__ colx, const unsigned int* __restrict__ colsup,
    float* __restrict__ out4) {
  int bx = blockIdx.x, t = threadIdx.x;
  const unsigned int* src; int n; float scale; int slot;
  if (bx < 32)      { src = rowmin + bx * 1024; n = 1024; scale = 1.f / BATCH; slot = 1; }
  else if (bx == 32){ src = colx;               n = 1024; scale = 1.f / NSUB;  slot = 0; }
  else if (bx == 33){ src = rowmin + BATCH;     n = 256;  scale = 1.f / NSUP;  slot = 2; }
  else              { src = colsup;             n = 1024; scale = 1.f / NSUB;  slot = 3; }
  float s = 0.f;
  for (int i = t; i < n; i += 256) s += __uint_as_float(src[i]);
  __shared__ float red[4];
  for (int off = 32; off; off >>= 1) s += __shfl_down(s, off);
  if ((t & 63) == 0) red[t >> 6] = s;
  __syncthreads();
  if (t == 0) atomicAdd(out4 + slot, (red[0] + red[1] + red[2] + red[3]) * scale);
}

extern "C" void kernel_launch(void* const* d_in, const int* in_sizes, int n_in,
                              void* d_out, int out_size, void* d_ws, size_t ws_size,
                              hipStream_t stream) {
  const float* x   = (const float*)d_in[0];
  const float* sup = (const float*)d_in[1];
  const float* sub = (const float*)d_in[2];
  const float* W1  = (const float*)d_in[3];
  const float* b1  = (const float*)d_in[4];
  const float* W2  = (const float*)d_in[5];
  const float* b2  = (const float*)d_in[6];
  float* out = (float*)d_out;

  char* p = (char*)d_ws;
  u16* Bext  = (u16*)p;            p += (size_t)(512 + NSUB) * LATENT * 2; // Mt(512) ++ subs(1024), contiguous
  u16* Mt    = Bext;
  u16* subs  = Bext + (size_t)512 * LATENT;
  u16* sups  = (u16*)p;            p += (size_t)NSUP * LATENT * 2;
  float* xxsup = (float*)p;        p += NSUP * 4;
  float* yys   = (float*)p;        p += NSUB * 4;
  float* sc    = (float*)p;        p += 512 * 4;
  float* cc    = (float*)p;        p += 512 * 4;
  unsigned int* rowmin = (unsigned int*)p; p += (size_t)(BATCH + NSUP) * 4; // then colx, colsup contiguous
  unsigned int* colx   = (unsigned int*)p; p += (size_t)NSUB * 4;
  unsigned int* colsup = (unsigned int*)p; p += (size_t)NSUB * 4;

  int initn = BATCH + NSUP + 2 * NSUB;   // 35072 = 137*256
  float* out4 = out + 2 * SUP_OFF;

  hipLaunchKernelGGL(k_convert_small, dim3((NSUP + NSUB) / 4), dim3(256), 0, stream,
                     sup, sub, sups, subs, xxsup, yys);
  hipLaunchKernelGGL(k_mt8, dim3(2, 64), dim3(256), 0, stream, sup, sub, W1, W2, Mt);
  hipLaunchKernelGGL(k_prep, dim3(139), dim3(256), 0, stream,
                     W1, b1, W2, b2, xxsup, yys, sc, cc, rowmin, initn, out4);
  hipLaunchKernelGGL(k_gemm_x, dim3(BATCH / 64), dim3(256), 0, stream,
                     x, Bext, yys, sc, cc, out, rowmin, colx);
  hipLaunchKernelGGL(k_sup, dim3(8, 2), dim3(256), 0, stream,
                     sups, subs, xxsup, yys, rowmin, colsup);
  hipLaunchKernelGGL(k_final2, dim3(35), dim3(256), 0, stream, rowmin, colx, colsup, out4);
}

// Round 4
// 315.638 us; speedup vs baseline: 1.1705x; 1.0322x over previous
//
#include <hip/hip_runtime.h>
#include <stdint.h>

#define BATCH   32768
#define NSUP    256
#define NSUB    1024
#define LATENT  512
#define NOUT    200
#define SUP_OFF ((size_t)BATCH * NOUT)  // sup_out offset in d_out

typedef unsigned short u16;
typedef __attribute__((ext_vector_type(8))) __bf16 bf16x8;
typedef __attribute__((ext_vector_type(4))) float  floatx4;

typedef const __attribute__((address_space(1))) void* gptr_t;
typedef __attribute__((address_space(3))) void* sptr_t;

__device__ __forceinline__ void gload16(const void* g, void* l) {
  __builtin_amdgcn_global_load_lds((gptr_t)g, (sptr_t)l, 16, 0, 0);
}

__device__ __forceinline__ floatx4 mfma_bf16(bf16x8 a, bf16x8 b, floatx4 c) {
  return __builtin_amdgcn_mfma_f32_16x16x32_bf16(a, b, c, 0, 0, 0);
}

__device__ __forceinline__ u16 f2bf(float f) {
  unsigned int u = __float_as_uint(f);
  u += 0x7FFFu + ((u >> 16) & 1u);   // RNE; inputs finite
  return (u16)(u >> 16);
}

// ---------------- one setup kernel: cvt sup+sub -> bf16 + norms; init mins; zero r-slots
// bx [0,320): convert 4 rows each (sup rows 0..255, then sub 0..1023)
// bx [320,457): init 35072 min-uints to +inf; bx 457: zero out4
__global__ __launch_bounds__(256) void k_setup(const float* __restrict__ sup,
    const float* __restrict__ sub, u16* __restrict__ sups, u16* __restrict__ subs,
    float* __restrict__ xxsup, float* __restrict__ yys,
    unsigned int* __restrict__ minbuf, float* __restrict__ out4) {
  int bx = blockIdx.x;
  if (bx >= 320) {
    if (bx == 457) { if (threadIdx.x < 4) out4[threadIdx.x] = 0.f; return; }
    int i = (bx - 320) * 256 + threadIdx.x;
    if (i < BATCH + NSUP + 2 * NSUB) minbuf[i] = 0x7F800000u;
    return;
  }
  int row  = bx * 4 + (threadIdx.x >> 6);
  int lane = threadIdx.x & 63;
  const float* src; u16* dst; float* nrm;
  if (row < NSUP) { src = sup + (size_t)row * LATENT; dst = sups + (size_t)row * LATENT; nrm = xxsup + row; }
  else { int r = row - NSUP; src = sub + (size_t)r * LATENT; dst = subs + (size_t)r * LATENT; nrm = yys + r; }
  const float* s = src + lane * 8;
  float4 v0 = ((const float4*)s)[0];
  float4 v1 = ((const float4*)s)[1];
  float ss = v0.x*v0.x + v0.y*v0.y + v0.z*v0.z + v0.w*v0.w
           + v1.x*v1.x + v1.y*v1.y + v1.z*v1.z + v1.w*v1.w;
  uint4 o;
  o.x = (unsigned)f2bf(v0.x) | ((unsigned)f2bf(v0.y) << 16);
  o.y = (unsigned)f2bf(v0.z) | ((unsigned)f2bf(v0.w) << 16);
  o.z = (unsigned)f2bf(v1.x) | ((unsigned)f2bf(v1.y) << 16);
  o.w = (unsigned)f2bf(v1.z) | ((unsigned)f2bf(v1.w) << 16);
  *((uint4*)(dst + lane * 8)) = o;
  for (int off = 32; off; off >>= 1) ss += __shfl_down(ss, off);
  if (lane == 0) *nrm = ss;
}

// ---------------- Mt build + wprep constants in one kernel
// bx [0,128): Mt[o][k] = -2 sum_j W[o,j] P[j,k] (8 outs/block; rows 400..511 zero)
// bx [128,228): sc/cc per output, one wave per output (coalesced W-row reads)
__global__ __launch_bounds__(256) void k_mt_w(const float* __restrict__ sup,
    const float* __restrict__ sub, const float* __restrict__ W1,
    const float* __restrict__ b1, const float* __restrict__ W2,
    const float* __restrict__ b2, const float* __restrict__ xxsup,
    const float* __restrict__ yys, u16* __restrict__ Mt,
    float* __restrict__ sc, float* __restrict__ cc) {
  int bx = blockIdx.x;
  if (bx >= 128) {
    int wave = threadIdx.x >> 6, lane = threadIdx.x & 63;
    int o = (bx - 128) * 4 + wave;
    if (o >= 400) return;
    int n; const float* Wr; const float* yy;
    if (o < 200) { n = NSUP; Wr = W1 + (size_t)o * NSUP; yy = xxsup; }
    else         { n = NSUB; Wr = W2 + (size_t)(o - 200) * NSUB; yy = yys; }
    float s = 0.f, c = 0.f;
    for (int j = lane; j < n; j += 64) { float w = Wr[j]; s += w; c += w * yy[j]; }
    for (int off = 32; off; off >>= 1) { s += __shfl_down(s, off); c += __shfl_down(c, off); }
    if (lane == 0) { sc[o] = s; cc[o] = c + ((o < 200) ? b1[o] : b2[o - 200]); }
    return;
  }
  __shared__ float lw[8 * 1024];
  int k  = (bx & 1) * 256 + threadIdx.x;
  int o0 = (bx >> 1) * 8;
  if (o0 >= 400) {
    for (int oo = 0; oo < 8; oo++) Mt[(size_t)(o0 + oo) * LATENT + k] = 0;
    return;
  }
  const float* P; const float* W; int n, ow;
  if (o0 < 200) { P = sup; W = W1; n = NSUP;  ow = o0; }
  else          { P = sub; W = W2; n = NSUB;  ow = o0 - 200; }
  for (int idx = threadIdx.x; idx < 8 * n; idx += 256) {
    int oo = idx / n, j = idx & (n - 1);
    lw[oo * 1024 + j] = W[(size_t)(ow + oo) * n + j];
  }
  __syncthreads();
  float a[8] = {};
  for (int j = 0; j < n; j++) {
    float pv = P[(size_t)j * LATENT + k];
#pragma unroll
    for (int oo = 0; oo < 8; oo++) a[oo] += pv * lw[oo * 1024 + j];
  }
#pragma unroll
  for (int oo = 0; oo < 8; oo++) Mt[(size_t)(o0 + oo) * LATENT + k] = f2bf(-2.f * a[oo]);
}

// ---------------- THE kernel: 512 threads, 8 waves share one 64-row A tile (LDS),
// each wave owns a 32-col strip per 256-col phase. B read from L2. Barrier-free K-loop.
// Grid 512 blocks = 2 blocks/CU = 16 waves/CU = 4 waves/SIMD.
__global__ __launch_bounds__(512, 4) void k_gemm_x(const float* __restrict__ x,
    const u16* __restrict__ Bext, const float* __restrict__ yys,
    const float* __restrict__ sc, const float* __restrict__ cc,
    float* __restrict__ out, unsigned int* __restrict__ rowmin,
    unsigned int* __restrict__ colx) {
  __shared__ __align__(16) u16 lA[64 * 512];   // 64 KB, 16B-chunk XOR-8 swizzle
  __shared__ float lxx[64];
  int t = threadIdx.x, wave = t >> 6, lane = t & 63;
  int l16 = lane & 15, qq = lane >> 4;
  size_t arow0 = (size_t)blockIdx.x * 64;

  // ---- stage A: fp32 -> bf16 LDS (swizzled) + row sum-of-squares
  const float* Ab = x + arow0 * LATENT;
#pragma unroll
  for (int i = 0; i < 8; i++) {
    int row = i * 8 + wave;
    const float* s = Ab + (size_t)row * LATENT + lane * 8;
    float4 v0 = ((const float4*)s)[0];
    float4 v1 = ((const float4*)s)[1];
    float ss = v0.x*v0.x + v0.y*v0.y + v0.z*v0.z + v0.w*v0.w
             + v1.x*v1.x + v1.y*v1.y + v1.z*v1.z + v1.w*v1.w;
    uint4 o;
    o.x = (unsigned)f2bf(v0.x) | ((unsigned)f2bf(v0.y) << 16);
    o.y = (unsigned)f2bf(v0.z) | ((unsigned)f2bf(v0.w) << 16);
    o.z = (unsigned)f2bf(v1.x) | ((unsigned)f2bf(v1.y) << 16);
    o.w = (unsigned)f2bf(v1.z) | ((unsigned)f2bf(v1.w) << 16);
    *((uint4*)(lA + ((row * 64) + (lane ^ (row & 7))) * 8)) = o;
    for (int off = 32; off; off >>= 1) ss += __shfl_down(ss, off);
    if (lane == 0) lxx[row] = ss;
  }
  __syncthreads();   // the ONLY barrier

  float xv[4][4];
#pragma unroll
  for (int mf = 0; mf < 4; mf++)
#pragma unroll
    for (int r = 0; r < 4; r++) xv[mf][r] = lxx[mf * 16 + qq * 4 + r];
  float rmreg[4][4];
#pragma unroll
  for (int mf = 0; mf < 4; mf++)
#pragma unroll
    for (int r = 0; r < 4; r++) rmreg[mf][r] = 3.4e38f;

#pragma unroll 1
  for (int p = 0; p < 6; p++) {            // 6 phases of 256 cols; wave strip = 32 cols
    floatx4 acc[4][2] = {};
    const u16* B0 = Bext + (size_t)(p * 256 + wave * 32) * LATENT;
#pragma unroll 2
    for (int k0 = 0; k0 < LATENT; k0 += 64) {
      bf16x8 bv[2][2];
#pragma unroll
      for (int nf = 0; nf < 2; nf++)
#pragma unroll
        for (int ks = 0; ks < 2; ks++)
          bv[nf][ks] = *(const bf16x8*)(B0 + (size_t)(nf * 16 + l16) * LATENT
                                           + k0 + ks * 32 + qq * 8);
#pragma unroll
      for (int ks = 0; ks < 2; ks++) {
        bf16x8 a[4];
#pragma unroll
        for (int mf = 0; mf < 4; mf++) {
          int row = mf * 16 + l16;
          int kc = (k0 >> 3) + ks * 4 + qq;
          a[mf] = *(const bf16x8*)(lA + ((row * 64) + (kc ^ (row & 7))) * 8);
        }
#pragma unroll
        for (int mf = 0; mf < 4; mf++)
#pragma unroll
          for (int nf = 0; nf < 2; nf++)
            acc[mf][nf] = mfma_bf16(a[mf], bv[nf][ks], acc[mf][nf]);
      }
    }
    if (p < 2) {
      // classifier heads: out = acc + xx*sc + cc (cols p*256 + wave*32 .., valid < 400)
      int colbase = p * 256 + wave * 32;
#pragma unroll
      for (int nf = 0; nf < 2; nf++) {
        int c = colbase + nf * 16 + l16;
        if (c < 400) {
          float scv = sc[c], ccv = cc[c];
#pragma unroll
          for (int mf = 0; mf < 4; mf++)
#pragma unroll
            for (int r = 0; r < 4; r++) {
              size_t row = arow0 + mf * 16 + qq * 4 + r;
              float v = acc[mf][nf][r] + xv[mf][r] * scv + ccv;
              size_t idx = (c < 200) ? (SUP_OFF + row * NOUT + c)
                                     : (row * NOUT + (c - 200));
              out[idx] = v;
            }
        }
      }
    } else {
      // distance mins: d = xx - 2*acc + yy (sub cols)
      int colbase = p * 256 + wave * 32 - 512;
#pragma unroll
      for (int nf = 0; nf < 2; nf++) {
        int cs = colbase + nf * 16 + l16;
        float yv = yys[cs];
        float cmin = 3.4e38f;
#pragma unroll
        for (int mf = 0; mf < 4; mf++)
#pragma unroll
          for (int r = 0; r < 4; r++) {
            float d = xv[mf][r] - 2.0f * acc[mf][nf][r] + yv;
            rmreg[mf][r] = fminf(rmreg[mf][r], d);
            cmin = fminf(cmin, d);
          }
        cmin = fminf(cmin, __shfl_xor(cmin, 16));
        cmin = fminf(cmin, __shfl_xor(cmin, 32));
        if (qq == 0) atomicMin(colx + cs, __float_as_uint(cmin));
      }
    }
  }
  // row mins: reduce across the 16 l16-lanes (cols), merge waves/blocks via atomics
#pragma unroll
  for (int mf = 0; mf < 4; mf++)
#pragma unroll
    for (int r = 0; r < 4; r++) {
      float v = rmreg[mf][r];
      v = fminf(v, __shfl_xor(v, 1));
      v = fminf(v, __shfl_xor(v, 2));
      v = fminf(v, __shfl_xor(v, 4));
      v = fminf(v, __shfl_xor(v, 8));
      if (l16 == 0) atomicMin(rowmin + arow0 + mf * 16 + qq * 4 + r, __float_as_uint(v));
    }
}

// ---------------- sup(256) x sub(1024) distances -> rowmin[BATCH..], colsup (r3,r4)
__global__ __launch_bounds__(256) void k_sup(const u16* __restrict__ A,
    const u16* __restrict__ subs, const float* __restrict__ xxsup,
    const float* __restrict__ yys, unsigned int* __restrict__ rowmin,
    unsigned int* __restrict__ colsup) {
  __shared__ __align__(16) u16 lA[128 * 64];
  __shared__ __align__(16) u16 lB[128 * 64];
  int cb = blockIdx.x;
  size_t arow0 = (size_t)blockIdx.y * 128;
  const u16* B = subs + (size_t)cb * 128 * LATENT;
  floatx4 acc[4][4] = {};
  int t = threadIdx.x, wave = t >> 6, lane = t & 63;
  int l16 = lane & 15, qq = lane >> 4;
  int wm = (wave >> 1) * 64, wn = (wave & 1) * 64;

  int sq = (lane & 7) ^ (lane >> 3);
  const u16* Ab = A + arow0 * LATENT;
  int soff[4]; u16 *dA[4], *dB[4];
#pragma unroll
  for (int i = 0; i < 4; i++) {
    int s = i * 256 + t;
    soff[i] = (s >> 3) * LATENT + sq * 8;
    int sbase = (i * 256 + wave * 64) * 8;
    dA[i] = lA + sbase; dB[i] = lB + sbase;
  }
  for (int k0 = 0; k0 < LATENT; k0 += 64) {
#pragma unroll
    for (int i = 0; i < 4; i++) gload16(Ab + soff[i] + k0, dA[i]);
#pragma unroll
    for (int i = 0; i < 4; i++) gload16(B  + soff[i] + k0, dB[i]);
    __syncthreads();
#pragma unroll
    for (int ks = 0; ks < 2; ks++) {
      bf16x8 af[4], bvv[4];
      int sw = ((ks * 4 + qq) ^ (l16 & 7)) * 8;
#pragma unroll
      for (int f = 0; f < 4; f++) {
        af[f]  = *(const bf16x8*)(lA + (wm + f * 16 + l16) * 64 + sw);
        bvv[f] = *(const bf16x8*)(lB + (wn + f * 16 + l16) * 64 + sw);
      }
#pragma unroll
      for (int fm = 0; fm < 4; fm++)
#pragma unroll
        for (int fn = 0; fn < 4; fn++)
          acc[fm][fn] = mfma_bf16(af[fm], bvv[fn], acc[fm][fn]);
    }
    __syncthreads();
  }
  int colb = cb * 128 + wn + l16;
  float yv[4];
#pragma unroll
  for (int fn = 0; fn < 4; fn++) yv[fn] = yys[colb + fn * 16];
  float cmin[4] = {3.4e38f, 3.4e38f, 3.4e38f, 3.4e38f};
#pragma unroll
  for (int fm = 0; fm < 4; fm++) {
#pragma unroll
    for (int r = 0; r < 4; r++) {
      int row = (int)arow0 + wm + fm * 16 + qq * 4 + r;
      float xvv = xxsup[row];
      float rmin = 3.4e38f;
#pragma unroll
      for (int fn = 0; fn < 4; fn++) {
        float d = xvv - 2.0f * acc[fm][fn][r] + yv[fn];
        rmin = fminf(rmin, d);
        cmin[fn] = fminf(cmin[fn], d);
      }
      for (int off = 1; off < 16; off <<= 1) rmin = fminf(rmin, __shfl_xor(rmin, off));
      if (l16 == 0) atomicMin(rowmin + BATCH + row, __float_as_uint(rmin));
    }
  }
#pragma unroll
  for (int fn = 0; fn < 4; fn++) {
    float v = cmin[fn];
    v = fminf(v, __shfl_xor(v, 16));
    v = fminf(v, __shfl_xor(v, 32));
    if (qq == 0) atomicMin(colsup + colb + fn * 16, __float_as_uint(v));
  }
}

// ---------------- parallel means of mins -> r1,r2,r3,r4 (atomicAdd partials)
__global__ __launch_bounds__(256) void k_final2(const unsigned int* __restrict__ rowmin,
    const unsigned int* __restrict__ colx, const unsigned int* __restrict__ colsup,
    float* __restrict__ out4) {
  int bx = blockIdx.x, t = threadIdx.x;
  const unsigned int* src; int n; float scale; int slot;
  if (bx < 32)      { src = rowmin + bx * 1024; n = 1024; scale = 1.f / BATCH; slot = 1; }
  else if (bx == 32){ src = colx;               n = 1024; scale = 1.f / NSUB;  slot = 0; }
  else if (bx == 33){ src = rowmin + BATCH;     n = 256;  scale = 1.f / NSUP;  slot = 2; }
  else              { src = colsup;             n = 1024; scale = 1.f / NSUB;  slot = 3; }
  float s = 0.f;
  for (int i = t; i < n; i += 256) s += __uint_as_float(src[i]);
  __shared__ float red[4];
  for (int off = 32; off; off >>= 1) s += __shfl_down(s, off);
  if ((t & 63) == 0) red[t >> 6] = s;
  __syncthreads();
  if (t == 0) atomicAdd(out4 + slot, (red[0] + red[1] + red[2] + red[3]) * scale);
}

extern "C" void kernel_launch(void* const* d_in, const int* in_sizes, int n_in,
                              void* d_out, int out_size, void* d_ws, size_t ws_size,
                              hipStream_t stream) {
  const float* x   = (const float*)d_in[0];
  const float* sup = (const float*)d_in[1];
  const float* sub = (const float*)d_in[2];
  const float* W1  = (const float*)d_in[3];
  const float* b1  = (const float*)d_in[4];
  const float* W2  = (const float*)d_in[5];
  const float* b2  = (const float*)d_in[6];
  float* out = (float*)d_out;

  char* p = (char*)d_ws;
  u16* Bext  = (u16*)p;            p += (size_t)(512 + NSUB) * LATENT * 2; // Mt(512) ++ subs(1024)
  u16* Mt    = Bext;
  u16* subs  = Bext + (size_t)512 * LATENT;
  u16* sups  = (u16*)p;            p += (size_t)NSUP * LATENT * 2;
  float* xxsup = (float*)p;        p += NSUP * 4;
  float* yys   = (float*)p;        p += NSUB * 4;
  float* sc    = (float*)p;        p += 512 * 4;
  float* cc    = (float*)p;        p += 512 * 4;
  unsigned int* rowmin = (unsigned int*)p; p += (size_t)(BATCH + NSUP) * 4;
  unsigned int* colx   = (unsigned int*)p; p += (size_t)NSUB * 4;
  unsigned int* colsup = (unsigned int*)p; p += (size_t)NSUB * 4;

  float* out4 = out + 2 * SUP_OFF;

  hipLaunchKernelGGL(k_setup, dim3(458), dim3(256), 0, stream,
                     sup, sub, sups, subs, xxsup, yys, rowmin, out4);
  hipLaunchKernelGGL(k_mt_w, dim3(228), dim3(256), 0, stream,
                     sup, sub, W1, b1, W2, b2, xxsup, yys, Mt, sc, cc);
  hipLaunchKernelGGL(k_gemm_x, dim3(BATCH / 64), dim3(512), 0, stream,
                     x, Bext, yys, sc, cc, out, rowmin, colx);
  hipLaunchKernelGGL(k_sup, dim3(8, 2), dim3(256), 0, stream,
                     sups, subs, xxsup, yys, rowmin, colsup);
  hipLaunchKernelGGL(k_final2, dim3(35), dim3(256), 0, stream, rowmin, colx, colsup, out4);
}